// Round 10
// baseline (312.698 us; speedup 1.0000x reference)
//
#include <hip/hip_runtime.h>

#define N_NODES 50000
#define N_EDGES 800000
#define BN_EPS 1e-5f
#define NPAD 50176          // N_NODES padded to 98*512
#define SCAN_BLOCKS 98      // 98*512 = 50176

// CSR-build tiling: 32 edge slices x 4 node ranges of 16384 bins (packed LDS counters)
#define S_SLICES 32
#define R_RANGES 4
#define BINS 16384
#define NP4 (R_RANGES * BINS)        // 65536 bins per slice
#define ES (N_EDGES / S_SLICES)      // 25000 edges per slice

#define XS_STRIDE 68                 // LDS row stride in uints: bank spread

typedef unsigned int uint;
typedef unsigned short ushort;
typedef float floatx4 __attribute__((ext_vector_type(4)));
typedef short bf16x8 __attribute__((ext_vector_type(8)));

// ---- bf16 helpers ----
__device__ __forceinline__ float bfl(uint u) { return __uint_as_float(u << 16); }
__device__ __forceinline__ float bfh(uint u) { return __uint_as_float(u & 0xffff0000u); }
__device__ __forceinline__ uint pack_bf2(float a, float b) {
    uint ua = __float_as_uint(a), ub = __float_as_uint(b);
    ua += 0x7fffu + ((ua >> 16) & 1u);   // RNE
    ub += 0x7fffu + ((ub >> 16) & 1u);
    return (ua >> 16) | (ub & 0xffff0000u);
}
__device__ __forceinline__ ushort bf1(float x) {
    uint u = __float_as_uint(x);
    u += 0x7fffu + ((u >> 16) & 1u);
    return (ushort)(u >> 16);
}
__device__ __forceinline__ void acc8(float* a, uint4 h, float w) {
    a[0] += w * bfl(h.x); a[1] += w * bfh(h.x);
    a[2] += w * bfl(h.y); a[3] += w * bfh(h.y);
    a[4] += w * bfl(h.z); a[5] += w * bfh(h.z);
    a[6] += w * bfl(h.w); a[7] += w * bfh(h.w);
}

// ---------------- weight prep: W1[k][n]->W1t bf16[n][k], W2 likewise ----------------
__global__ __launch_bounds__(256) void prep_w_kernel(const float* __restrict__ W1,
                                                     const float* __restrict__ W2,
                                                     uint* __restrict__ W1t,
                                                     uint* __restrict__ W2t) {
    int t = blockIdx.x * 256 + threadIdx.x;
    if (t < 8192) {
        int n = t >> 6, kk = t & 63;
        W1t[t] = pack_bf2(W1[(2 * kk) * 128 + n], W1[(2 * kk + 1) * 128 + n]);
    } else if (t < 12288) {
        int u = t - 8192;
        int n = u >> 6, kk = u & 63;
        W2t[u] = pack_bf2(W2[(2 * kk) * 64 + n], W2[(2 * kk + 1) * 64 + n]);
    }
}

// ---------------- count: packed LDS histograms per (slice, range) ----------------
__global__ __launch_bounds__(256) void count_hist_kernel(const int* __restrict__ src,
                                                         const int* __restrict__ dst,
                                                         ushort* __restrict__ part_cnt,
                                                         ushort* __restrict__ part_deg) {
    __shared__ uint cnt_lds[BINS / 2];   // 2 bins per uint (16-bit fields)
    __shared__ uint deg_lds[BINS / 2];
    const int s = blockIdx.x / R_RANGES;
    const int r = blockIdx.x % R_RANGES;
    const int base = r * BINS;
    for (int j = threadIdx.x; j < BINS / 2; j += 256) { cnt_lds[j] = 0u; deg_lds[j] = 0u; }
    __syncthreads();
    const int e0 = s * ES;
    for (int i = threadIdx.x; i < ES; i += 256) {
        int e = e0 + i;
        int ss = src[e], dd = dst[e];
        if (ss != dd) {
            int a = ss - base;
            if ((unsigned)a < (unsigned)BINS) atomicAdd(&cnt_lds[a >> 1], 1u << ((a & 1) * 16));
            int b = dd - base;
            if ((unsigned)b < (unsigned)BINS) atomicAdd(&deg_lds[b >> 1], 1u << ((b & 1) * 16));
        }
    }
    __syncthreads();
    uint* pc = (uint*)&part_cnt[s * NP4 + base];
    uint* pd = (uint*)&part_deg[s * NP4 + base];
    for (int j = threadIdx.x; j < BINS / 2; j += 256) { pc[j] = cnt_lds[j]; pd[j] = deg_lds[j]; }
}

// ---------------- reduce partials: dinv + total rowcnt (2 nodes/thread) ----------------
__global__ __launch_bounds__(256) void dinv_rowcnt_kernel(const ushort* __restrict__ part_deg,
                                                          const ushort* __restrict__ part_cnt,
                                                          float* __restrict__ dinv,
                                                          int* __restrict__ rowcnt) {
    int i = (blockIdx.x * 256 + threadIdx.x) * 2;   // i < NPAD, even
    uint dg0 = 0, dg1 = 0, rc0 = 0, rc1 = 0;
#pragma unroll 8
    for (int s = 0; s < S_SLICES; ++s) {
        uint vd = *(const uint*)&part_deg[s * NP4 + i];
        uint vc = *(const uint*)&part_cnt[s * NP4 + i];
        dg0 += vd & 0xffffu; dg1 += vd >> 16;
        rc0 += vc & 0xffffu; rc1 += vc >> 16;
    }
    *(int2*)&rowcnt[i] = make_int2((int)rc0, (int)rc1);
    if (i < N_NODES) dinv[i] = rsqrtf((float)dg0 + 1.0f);
    if (i + 1 < N_NODES) dinv[i + 1] = rsqrtf((float)dg1 + 1.0f);
}

// ---------------- scan: per-block inclusive, then serial block sums ----------------
__global__ __launch_bounds__(512) void scan1_kernel(const int* __restrict__ rowcnt,
                                                    int* __restrict__ rowptr,
                                                    int* __restrict__ psum) {
    __shared__ int buf[512];
    int t = threadIdx.x;
    int g = blockIdx.x * 512 + t;
    buf[t] = rowcnt[g];
    __syncthreads();
#pragma unroll
    for (int off = 1; off < 512; off <<= 1) {
        int x = (t >= off) ? buf[t - off] : 0;
        __syncthreads();
        buf[t] += x;
        __syncthreads();
    }
    rowptr[g] = buf[t];
    if (t == 511) psum[blockIdx.x] = buf[511];
}

__global__ void scan2_kernel(int* __restrict__ psum) {
    if (threadIdx.x == 0) {
        int acc = 0;
        for (int i = 0; i < SCAN_BLOCKS; ++i) {
            int v = psum[i];
            psum[i] = acc;
            acc += v;
        }
    }
}

// ---------------- finalize rowptr (exclusive) + per-(slice,node) cursor bases --------
__global__ __launch_bounds__(256) void cursor_init_kernel(const int* __restrict__ rowcnt,
                                                          int* __restrict__ rowptr,
                                                          const int* __restrict__ psum,
                                                          const ushort* __restrict__ part_cnt,
                                                          int* __restrict__ cursor) {
    int i = (blockIdx.x * 256 + threadIdx.x) * 2;   // i < NPAD, even
    int ps = psum[i >> 9];
    int b0 = rowptr[i] - rowcnt[i] + ps;
    int b1 = rowptr[i + 1] - rowcnt[i + 1] + ps;
    *(int2*)&rowptr[i] = make_int2(b0, b1);
#pragma unroll 8
    for (int s = 0; s < S_SLICES; ++s) {
        *(int2*)&cursor[s * NP4 + i] = make_int2(b0, b1);
        uint vc = *(const uint*)&part_cnt[s * NP4 + i];
        b0 += (int)(vc & 0xffffu);
        b1 += (int)(vc >> 16);
    }
}

// ---------------- fill CSR via LDS cursors: (col, weight) pairs ----------------
__global__ __launch_bounds__(256) void fill_lds_kernel(const int* __restrict__ src,
                                                       const int* __restrict__ dst,
                                                       const float* __restrict__ dinv,
                                                       const int* __restrict__ cursor,
                                                       int2* __restrict__ epair) {
    __shared__ int curs[BINS];   // 64 KB
    const int s = blockIdx.x / R_RANGES;
    const int r = blockIdx.x % R_RANGES;
    const int base = r * BINS;
    const int* gc = &cursor[s * NP4 + base];
    for (int j = threadIdx.x; j < BINS; j += 256) curs[j] = gc[j];
    __syncthreads();
    const int e0 = s * ES;
    for (int i = threadIdx.x; i < ES; i += 256) {
        int e = e0 + i;
        int ss = src[e], dd = dst[e];
        int a = ss - base;
        if (ss != dd && (unsigned)a < (unsigned)BINS) {
            int pos = atomicAdd(&curs[a], 1);
            epair[pos] = make_int2(dd, __float_as_int(dinv[ss] * dinv[dd]));
        }
    }
}

// ---------------- GEMM1 (MFMA): Hbf = bf16(X @ W1 + b1), 64-row tiles ----------------
__global__ __launch_bounds__(256) void gemm1_mfma_kernel(const float* __restrict__ X,
                                                         const uint* __restrict__ W1t,
                                                         const float* __restrict__ bias,
                                                         ushort* __restrict__ Hbf) {
    __shared__ uint lds[(64 + 128) * XS_STRIDE];
    uint* Xs = lds;
    uint* Ws = lds + 64 * XS_STRIDE;
    const int t = threadIdx.x;
    const int rowBase = blockIdx.x * 64;

    {
        int r = t >> 2, q = t & 3;
        int arow = rowBase + r;
        uint* xd = &Xs[r * XS_STRIDE + q * 16];
        if (arow < N_NODES) {
            const float4* xp = (const float4*)&X[arow * 128 + q * 32];
#pragma unroll
            for (int i = 0; i < 8; ++i) {
                float4 v = xp[i];
                xd[2 * i]     = pack_bf2(v.x, v.y);
                xd[2 * i + 1] = pack_bf2(v.z, v.w);
            }
        } else {
#pragma unroll
            for (int i = 0; i < 16; ++i) xd[i] = 0u;
        }
    }
    {
        int n = t >> 1, half = t & 1;
        const uint4* wp = (const uint4*)&W1t[n * 64 + half * 32];
        uint* wd = &Ws[n * XS_STRIDE + half * 32];
#pragma unroll
        for (int i = 0; i < 8; ++i) *(uint4*)&wd[i * 4] = wp[i];
    }
    __syncthreads();

    const int wv = t >> 6, lane = t & 63;
    const int lr = lane & 15;
    const int ko = (lane >> 4) * 4;
    const int m0 = wv * 16;
    floatx4 acc[8];
#pragma unroll
    for (int j = 0; j < 8; ++j) acc[j] = (floatx4){0.f, 0.f, 0.f, 0.f};

#pragma unroll
    for (int ks = 0; ks < 4; ++ks) {
        const int kb = ks * 16 + ko;
        bf16x8 a = *(bf16x8*)&Xs[(m0 + lr) * XS_STRIDE + kb];
#pragma unroll
        for (int j = 0; j < 8; ++j) {
            bf16x8 b = *(bf16x8*)&Ws[(j * 16 + lr) * XS_STRIDE + kb];
            acc[j] = __builtin_amdgcn_mfma_f32_16x16x32_bf16(a, b, acc[j], 0, 0, 0);
        }
    }
    const int rbase = rowBase + m0 + (lane >> 4) * 4;
#pragma unroll
    for (int j = 0; j < 8; ++j) {
        const int col = j * 16 + lr;
        const float bb = bias[col];
#pragma unroll
        for (int r = 0; r < 4; ++r) {
            int row = rbase + r;
            if (row < N_NODES) Hbf[row * 128 + col] = bf1(acc[j][r] + bb);
        }
    }
}

// ---------------- GEMM2 (MFMA): Hbf = bf16(relu(bn(bf16 Hin)) @ W2 + b2) ------------
__global__ __launch_bounds__(256) void gemm2_mfma_kernel(const uint* __restrict__ Hin,
                                                         const uint* __restrict__ W2t,
                                                         const float* __restrict__ bias,
                                                         const float* __restrict__ scale,
                                                         const float* __restrict__ shift,
                                                         ushort* __restrict__ Hbf) {
    __shared__ uint lds[(64 + 64) * XS_STRIDE];
    uint* Xs = lds;
    uint* Ws = lds + 64 * XS_STRIDE;
    const int t = threadIdx.x;
    const int rowBase = blockIdx.x * 64;

    {
        int r = t >> 2, q = t & 3;
        int arow = rowBase + r;
        uint* xd = &Xs[r * XS_STRIDE + q * 16];
        if (arow < N_NODES) {
            const uint* hp = &Hin[arow * 64 + q * 16];
#pragma unroll
            for (int i = 0; i < 16; ++i) {
                uint u = hp[i];
                int m = q * 16 + i;
                float2 sc = *(const float2*)&scale[2 * m];
                float2 sh = *(const float2*)&shift[2 * m];
                float a0 = fmaxf(0.f, bfl(u) * sc.x + sh.x);
                float a1 = fmaxf(0.f, bfh(u) * sc.y + sh.y);
                xd[i] = pack_bf2(a0, a1);
            }
        } else {
#pragma unroll
            for (int i = 0; i < 16; ++i) xd[i] = 0u;
        }
    }
    if (t < 128) {
        int n = t >> 1, half = t & 1;
        const uint4* wp = (const uint4*)&W2t[n * 64 + half * 32];
        uint* wd = &Ws[n * XS_STRIDE + half * 32];
#pragma unroll
        for (int i = 0; i < 8; ++i) *(uint4*)&wd[i * 4] = wp[i];
    }
    __syncthreads();

    const int wv = t >> 6, lane = t & 63;
    const int lr = lane & 15;
    const int ko = (lane >> 4) * 4;
    const int m0 = wv * 16;
    floatx4 acc[4];
#pragma unroll
    for (int j = 0; j < 4; ++j) acc[j] = (floatx4){0.f, 0.f, 0.f, 0.f};

#pragma unroll
    for (int ks = 0; ks < 4; ++ks) {
        const int kb = ks * 16 + ko;
        bf16x8 a = *(bf16x8*)&Xs[(m0 + lr) * XS_STRIDE + kb];
#pragma unroll
        for (int j = 0; j < 4; ++j) {
            bf16x8 b = *(bf16x8*)&Ws[(j * 16 + lr) * XS_STRIDE + kb];
            acc[j] = __builtin_amdgcn_mfma_f32_16x16x32_bf16(a, b, acc[j], 0, 0, 0);
        }
    }
    const int rbase = rowBase + m0 + (lane >> 4) * 4;
#pragma unroll
    for (int j = 0; j < 4; ++j) {
        const int col = j * 16 + lr;
        const float bb = bias[col];
#pragma unroll
        for (int r = 0; r < 4; ++r) {
            int row = rbase + r;
            if (row < N_NODES) Hbf[row * 64 + col] = bf1(acc[j][r] + bb);
        }
    }
}

// ---------------- CSR gather SpMM over bf16 H, fp32 accumulate ----------------
// epair loaded 2-edges-per-int4; gather loop unrolled to 8 outstanding loads.
template <int C, bool OUT_BF16>
__global__ __launch_bounds__(256) void spmm_bf16_kernel(const int* __restrict__ rowptr,
                                                        const int2* __restrict__ epair,
                                                        const float* __restrict__ dinv,
                                                        const uint* __restrict__ H,
                                                        void* __restrict__ outv) {
    constexpr int LPR = C / 8;        // lanes per row
    constexpr int RPB = 256 / LPR;    // rows per block
    constexpr int US  = C / 2;        // uint row stride
    const int t = threadIdx.x;
    const int lane = t % LPR;
    const int row = blockIdx.x * RPB + t / LPR;
    if (row >= N_NODES) return;
    const int cu = lane * 4;
    const float di = dinv[row];

    float acc[8];
    {
        uint4 hv = *(const uint4*)&H[row * US + cu];
        float w = di * di;
        acc[0] = w * bfl(hv.x); acc[1] = w * bfh(hv.x);
        acc[2] = w * bfl(hv.y); acc[3] = w * bfh(hv.y);
        acc[4] = w * bfl(hv.z); acc[5] = w * bfh(hv.z);
        acc[6] = w * bfl(hv.w); acc[7] = w * bfh(hv.w);
    }
    const int e0 = rowptr[row], e1 = rowptr[row + 1];
    int e = e0;
    // peel to even edge index so int4 (2-edge) loads are 16B-aligned
    if ((e & 1) && e < e1) {
        int2 p = epair[e];
        uint4 h = *(const uint4*)&H[p.x * US + cu];
        acc8(acc, h, __int_as_float(p.y));
        ++e;
    }
    const int4* ep4 = (const int4*)epair;
    for (; e + 8 <= e1; e += 8) {
        int4 qa = ep4[(e >> 1) + 0];
        int4 qb = ep4[(e >> 1) + 1];
        int4 qc = ep4[(e >> 1) + 2];
        int4 qd = ep4[(e >> 1) + 3];
        uint4 h0 = *(const uint4*)&H[qa.x * US + cu];
        uint4 h1 = *(const uint4*)&H[qa.z * US + cu];
        uint4 h2 = *(const uint4*)&H[qb.x * US + cu];
        uint4 h3 = *(const uint4*)&H[qb.z * US + cu];
        uint4 h4 = *(const uint4*)&H[qc.x * US + cu];
        uint4 h5 = *(const uint4*)&H[qc.z * US + cu];
        uint4 h6 = *(const uint4*)&H[qd.x * US + cu];
        uint4 h7 = *(const uint4*)&H[qd.z * US + cu];
        acc8(acc, h0, __int_as_float(qa.y));
        acc8(acc, h1, __int_as_float(qa.w));
        acc8(acc, h2, __int_as_float(qb.y));
        acc8(acc, h3, __int_as_float(qb.w));
        acc8(acc, h4, __int_as_float(qc.y));
        acc8(acc, h5, __int_as_float(qc.w));
        acc8(acc, h6, __int_as_float(qd.y));
        acc8(acc, h7, __int_as_float(qd.w));
    }
    for (; e + 2 <= e1; e += 2) {
        int4 q = ep4[e >> 1];
        uint4 h0 = *(const uint4*)&H[q.x * US + cu];
        uint4 h1 = *(const uint4*)&H[q.z * US + cu];
        acc8(acc, h0, __int_as_float(q.y));
        acc8(acc, h1, __int_as_float(q.w));
    }
    if (e < e1) {
        int2 p = epair[e];
        uint4 h = *(const uint4*)&H[p.x * US + cu];
        acc8(acc, h, __int_as_float(p.y));
    }
    if (OUT_BF16) {
        uint4 o;
        o.x = pack_bf2(acc[0], acc[1]);
        o.y = pack_bf2(acc[2], acc[3]);
        o.z = pack_bf2(acc[4], acc[5]);
        o.w = pack_bf2(acc[6], acc[7]);
        *(uint4*)&((uint*)outv)[row * US + cu] = o;
    } else {
        float* out = (float*)outv;
        *(float4*)&out[row * C + lane * 8]     = make_float4(acc[0], acc[1], acc[2], acc[3]);
        *(float4*)&out[row * C + lane * 8 + 4] = make_float4(acc[4], acc[5], acc[6], acc[7]);
    }
}

// ---------------- BN statistics over bf16 h1agg ----------------
__global__ __launch_bounds__(256) void bn_stats_kernel(const uint* __restrict__ H,
                                                       float* __restrict__ sum,
                                                       float* __restrict__ sumsq) {
    int uc = threadIdx.x & 63;       // uint column (2 channels)
    int quarter = threadIdx.x >> 6;
    float s0 = 0.f, q0 = 0.f, s1 = 0.f, q1 = 0.f;
    for (int r = blockIdx.x * 4 + quarter; r < N_NODES; r += 512) {
        uint u = H[r * 64 + uc];
        float a = bfl(u), b = bfh(u);
        s0 += a; q0 += a * a;
        s1 += b; q1 += b * b;
    }
    __shared__ float red[4][256];
    red[0][threadIdx.x] = s0; red[1][threadIdx.x] = q0;
    red[2][threadIdx.x] = s1; red[3][threadIdx.x] = q1;
    __syncthreads();
    if (quarter == 0) {
        float ts0 = 0.f, tq0 = 0.f, ts1 = 0.f, tq1 = 0.f;
#pragma unroll
        for (int k = 0; k < 4; ++k) {
            ts0 += red[0][k * 64 + uc]; tq0 += red[1][k * 64 + uc];
            ts1 += red[2][k * 64 + uc]; tq1 += red[3][k * 64 + uc];
        }
        atomicAdd(&sum[2 * uc], ts0);
        atomicAdd(&sum[2 * uc + 1], ts1);
        atomicAdd(&sumsq[2 * uc], tq0);
        atomicAdd(&sumsq[2 * uc + 1], tq1);
    }
}

__global__ void bn_finalize_kernel(const float* __restrict__ sum,
                                   const float* __restrict__ sumsq,
                                   const float* __restrict__ gamma,
                                   const float* __restrict__ beta,
                                   float* __restrict__ scale,
                                   float* __restrict__ shift) {
    int c = threadIdx.x;
    if (c < 128) {
        float mean = sum[c] * (1.0f / N_NODES);
        float var = sumsq[c] * (1.0f / N_NODES) - mean * mean;
        float sc = gamma[c] * rsqrtf(var + BN_EPS);
        scale[c] = sc;
        shift[c] = beta[c] - mean * sc;
    }
}

extern "C" void kernel_launch(void* const* d_in, const int* in_sizes, int n_in,
                              void* d_out, int out_size, void* d_ws, size_t ws_size,
                              hipStream_t stream) {
    const float* x     = (const float*)d_in[0];
    const int*   ei    = (const int*)d_in[1];
    const float* W1    = (const float*)d_in[2];
    const float* b1    = (const float*)d_in[3];
    const float* gamma = (const float*)d_in[4];
    const float* beta  = (const float*)d_in[5];
    const float* W2    = (const float*)d_in[6];
    const float* b2    = (const float*)d_in[7];
    float* out = (float*)d_out;
    const int* src = ei;
    const int* dst = ei + N_EDGES;

    // ---- workspace layout (4-byte words) ----
    float* ws     = (float*)d_ws;
    float* dinv   = ws;                              // NPAD
    float* stats  = ws + NPAD;                       // 512
    int*   psum   = (int*)(ws + NPAD + 512);         // 128
    int*   rowcnt = psum + 128;                      // NPAD
    int*   rowptr = rowcnt + NPAD;                   // NPAD
    float* big    = (float*)(rowptr + NPAD);
    // BIG region (word offsets), lifetime-disjoint aliases:
    //   epair    @ 0         [1.6M]     (fill -> spmms)
    //   part_cnt @ 1.6M      [1.049M]   (S*NP4 ushorts; dead after cursor_init)
    //   part_deg @ 2.7M      [1.049M]   (dead after dinv_rowcnt)
    //   cursor   @ 3.8M      [2.097M]   (S*NP4 ints; dead after fill)
    //   h1bf     @ 1.6M      [3.2M]     (gemm1 -> spmm1; aliases part arrays, dead by then)
    //   h1agg    @ 4.8M      [1.6M]     (spmm1 bf16 out; past cursor end by gemm2 time... 
    //                                    cursor dead after fill which precedes gemm1)
    //   W1t/W2t  @ 10.0M     [12K]
    int2*   epair    = (int2*)big;
    ushort* part_cnt = (ushort*)(big + 1600000);
    ushort* part_deg = (ushort*)(big + 2700000);
    int*    cursor   = (int*)(big + 3800000);
    ushort* h1bf     = (ushort*)(big + 1600000);
    uint*   h1agg    = (uint*)(big + 4800000);       // bf16 x128, packed pairs
    ushort* h2bf     = h1bf;                         // 64ch, fits in h1bf region
    uint*   W1t      = (uint*)(big + 10000000);
    uint*   W2t      = W1t + 8192;
    float* sum    = stats;
    float* sumsq  = stats + 128;
    float* scale  = stats + 256;
    float* shift  = stats + 384;

    hipMemsetAsync(stats, 0, 512 * sizeof(float), stream);

    prep_w_kernel<<<48, 256, 0, stream>>>(W1, W2, W1t, W2t);

    count_hist_kernel<<<S_SLICES * R_RANGES, 256, 0, stream>>>(src, dst, part_cnt, part_deg);
    dinv_rowcnt_kernel<<<NPAD / 512, 256, 0, stream>>>(part_deg, part_cnt, dinv, rowcnt);

    scan1_kernel<<<SCAN_BLOCKS, 512, 0, stream>>>(rowcnt, rowptr, psum);
    scan2_kernel<<<1, 64, 0, stream>>>(psum);
    cursor_init_kernel<<<NPAD / 512, 256, 0, stream>>>(rowcnt, rowptr, psum, part_cnt, cursor);
    fill_lds_kernel<<<S_SLICES * R_RANGES, 256, 0, stream>>>(src, dst, dinv, cursor, epair);

    gemm1_mfma_kernel<<<(N_NODES + 63) / 64, 256, 0, stream>>>(x, W1t, b1, h1bf);

    spmm_bf16_kernel<128, true><<<(N_NODES + 15) / 16, 256, 0, stream>>>(
        rowptr, epair, dinv, (const uint*)h1bf, (void*)h1agg);

    bn_stats_kernel<<<128, 256, 0, stream>>>(h1agg, sum, sumsq);
    bn_finalize_kernel<<<1, 128, 0, stream>>>(sum, sumsq, gamma, beta, scale, shift);

    gemm2_mfma_kernel<<<(N_NODES + 63) / 64, 256, 0, stream>>>(h1agg, W2t, b2, scale, shift, h2bf);

    spmm_bf16_kernel<64, false><<<(N_NODES + 31) / 32, 256, 0, stream>>>(
        rowptr, epair, dinv, (const uint*)h2bf, (void*)out);
}

// Round 11
// 256.731 us; speedup vs baseline: 1.2180x; 1.2180x over previous
//
#include <hip/hip_runtime.h>

#define N_NODES 50000
#define N_EDGES 800000
#define BN_EPS 1e-5f
#define NPAD 50176          // N_NODES padded to 98*512
#define SCAN_BLOCKS 98      // 98*512 = 50176

// CSR-build tiling: 64 edge slices x 4 node ranges of 16384 bins (packed LDS counters)
#define S_SLICES 64
#define R_RANGES 4
#define BINS 16384
#define NP4 (R_RANGES * BINS)        // 65536 bins per slice
#define ES (N_EDGES / S_SLICES)      // 12500 edges per slice (div by 4)

#define XS_STRIDE 68                 // LDS row stride in uints: bank spread

typedef unsigned int uint;
typedef unsigned short ushort;
typedef float floatx4 __attribute__((ext_vector_type(4)));
typedef short bf16x8 __attribute__((ext_vector_type(8)));

// ---- bf16 helpers ----
__device__ __forceinline__ float bfl(uint u) { return __uint_as_float(u << 16); }
__device__ __forceinline__ float bfh(uint u) { return __uint_as_float(u & 0xffff0000u); }
__device__ __forceinline__ uint pack_bf2(float a, float b) {
    uint ua = __float_as_uint(a), ub = __float_as_uint(b);
    ua += 0x7fffu + ((ua >> 16) & 1u);   // RNE
    ub += 0x7fffu + ((ub >> 16) & 1u);
    return (ua >> 16) | (ub & 0xffff0000u);
}
__device__ __forceinline__ ushort bf1(float x) {
    uint u = __float_as_uint(x);
    u += 0x7fffu + ((u >> 16) & 1u);
    return (ushort)(u >> 16);
}
__device__ __forceinline__ void acc8(float* a, uint4 h, float w) {
    a[0] += w * bfl(h.x); a[1] += w * bfh(h.x);
    a[2] += w * bfl(h.y); a[3] += w * bfh(h.y);
    a[4] += w * bfl(h.z); a[5] += w * bfh(h.z);
    a[6] += w * bfl(h.w); a[7] += w * bfh(h.w);
}

// ---------------- weight prep: W1[k][n]->W1t bf16[n][k], W2 likewise ----------------
__global__ __launch_bounds__(256) void prep_w_kernel(const float* __restrict__ W1,
                                                     const float* __restrict__ W2,
                                                     uint* __restrict__ W1t,
                                                     uint* __restrict__ W2t) {
    int t = blockIdx.x * 256 + threadIdx.x;
    if (t < 8192) {
        int n = t >> 6, kk = t & 63;
        W1t[t] = pack_bf2(W1[(2 * kk) * 128 + n], W1[(2 * kk + 1) * 128 + n]);
    } else if (t < 12288) {
        int u = t - 8192;
        int n = u >> 6, kk = u & 63;
        W2t[u] = pack_bf2(W2[(2 * kk) * 64 + n], W2[(2 * kk + 1) * 64 + n]);
    }
}

// ---------------- count: packed LDS histograms per (slice, range), int4 edge loads ---
__global__ __launch_bounds__(256) void count_hist_kernel(const int* __restrict__ src,
                                                         const int* __restrict__ dst,
                                                         ushort* __restrict__ part_cnt,
                                                         ushort* __restrict__ part_deg) {
    __shared__ uint cnt_lds[BINS / 2];   // 2 bins per uint (16-bit fields)
    __shared__ uint deg_lds[BINS / 2];
    const int s = blockIdx.x / R_RANGES;
    const int r = blockIdx.x % R_RANGES;
    const int base = r * BINS;
    for (int j = threadIdx.x; j < BINS / 2; j += 256) { cnt_lds[j] = 0u; deg_lds[j] = 0u; }
    __syncthreads();
    const int4* s4 = (const int4*)(src + s * ES);
    const int4* d4 = (const int4*)(dst + s * ES);
#pragma unroll 2
    for (int g = threadIdx.x; g < ES / 4; g += 256) {
        int4 sv = s4[g];
        int4 dv = d4[g];
#pragma unroll
        for (int k = 0; k < 4; ++k) {
            int ss = (&sv.x)[k], dd = (&dv.x)[k];
            if (ss != dd) {
                int a = ss - base;
                if ((unsigned)a < (unsigned)BINS)
                    atomicAdd(&cnt_lds[a >> 1], 1u << ((a & 1) * 16));
                int b = dd - base;
                if ((unsigned)b < (unsigned)BINS)
                    atomicAdd(&deg_lds[b >> 1], 1u << ((b & 1) * 16));
            }
        }
    }
    __syncthreads();
    uint* pc = (uint*)&part_cnt[s * NP4 + base];
    uint* pd = (uint*)&part_deg[s * NP4 + base];
    for (int j = threadIdx.x; j < BINS / 2; j += 256) { pc[j] = cnt_lds[j]; pd[j] = deg_lds[j]; }
}

// ---------------- reduce partials: dinv + total rowcnt (2 nodes/thread) ----------------
__global__ __launch_bounds__(256) void dinv_rowcnt_kernel(const ushort* __restrict__ part_deg,
                                                          const ushort* __restrict__ part_cnt,
                                                          float* __restrict__ dinv,
                                                          int* __restrict__ rowcnt) {
    int i = (blockIdx.x * 256 + threadIdx.x) * 2;   // i < NPAD, even
    uint dg0 = 0, dg1 = 0, rc0 = 0, rc1 = 0;
#pragma unroll 8
    for (int s = 0; s < S_SLICES; ++s) {
        uint vd = *(const uint*)&part_deg[s * NP4 + i];
        uint vc = *(const uint*)&part_cnt[s * NP4 + i];
        dg0 += vd & 0xffffu; dg1 += vd >> 16;
        rc0 += vc & 0xffffu; rc1 += vc >> 16;
    }
    *(int2*)&rowcnt[i] = make_int2((int)rc0, (int)rc1);
    if (i < N_NODES) dinv[i] = rsqrtf((float)dg0 + 1.0f);
    if (i + 1 < N_NODES) dinv[i + 1] = rsqrtf((float)dg1 + 1.0f);
}

// ---------------- scan: per-block inclusive, then serial block sums ----------------
__global__ __launch_bounds__(512) void scan1_kernel(const int* __restrict__ rowcnt,
                                                    int* __restrict__ rowptr,
                                                    int* __restrict__ psum) {
    __shared__ int buf[512];
    int t = threadIdx.x;
    int g = blockIdx.x * 512 + t;
    buf[t] = rowcnt[g];
    __syncthreads();
#pragma unroll
    for (int off = 1; off < 512; off <<= 1) {
        int x = (t >= off) ? buf[t - off] : 0;
        __syncthreads();
        buf[t] += x;
        __syncthreads();
    }
    rowptr[g] = buf[t];
    if (t == 511) psum[blockIdx.x] = buf[511];
}

__global__ void scan2_kernel(int* __restrict__ psum) {
    if (threadIdx.x == 0) {
        int acc = 0;
        for (int i = 0; i < SCAN_BLOCKS; ++i) {
            int v = psum[i];
            psum[i] = acc;
            acc += v;
        }
    }
}

// ---------------- finalize rowptr (exclusive) + per-(slice,node) cursor bases --------
__global__ __launch_bounds__(256) void cursor_init_kernel(const int* __restrict__ rowcnt,
                                                          int* __restrict__ rowptr,
                                                          const int* __restrict__ psum,
                                                          const ushort* __restrict__ part_cnt,
                                                          int* __restrict__ cursor) {
    int i = (blockIdx.x * 256 + threadIdx.x) * 2;   // i < NPAD, even
    int ps = psum[i >> 9];
    int b0 = rowptr[i] - rowcnt[i] + ps;
    int b1 = rowptr[i + 1] - rowcnt[i + 1] + ps;
    *(int2*)&rowptr[i] = make_int2(b0, b1);
#pragma unroll 8
    for (int s = 0; s < S_SLICES; ++s) {
        *(int2*)&cursor[s * NP4 + i] = make_int2(b0, b1);
        uint vc = *(const uint*)&part_cnt[s * NP4 + i];
        b0 += (int)(vc & 0xffffu);
        b1 += (int)(vc >> 16);
    }
}

// ---------------- fill CSR via LDS cursors, int4 edge loads ----------------
__global__ __launch_bounds__(256) void fill_lds_kernel(const int* __restrict__ src,
                                                       const int* __restrict__ dst,
                                                       const float* __restrict__ dinv,
                                                       const int* __restrict__ cursor,
                                                       int2* __restrict__ epair) {
    __shared__ int curs[BINS];   // 64 KB
    const int s = blockIdx.x / R_RANGES;
    const int r = blockIdx.x % R_RANGES;
    const int base = r * BINS;
    const int* gc = &cursor[s * NP4 + base];
    for (int j = threadIdx.x; j < BINS; j += 256) curs[j] = gc[j];
    __syncthreads();
    const int4* s4 = (const int4*)(src + s * ES);
    const int4* d4 = (const int4*)(dst + s * ES);
#pragma unroll 2
    for (int g = threadIdx.x; g < ES / 4; g += 256) {
        int4 sv = s4[g];
        int4 dv = d4[g];
#pragma unroll
        for (int k = 0; k < 4; ++k) {
            int ss = (&sv.x)[k], dd = (&dv.x)[k];
            int a = ss - base;
            if (ss != dd && (unsigned)a < (unsigned)BINS) {
                int pos = atomicAdd(&curs[a], 1);
                epair[pos] = make_int2(dd, __float_as_int(dinv[ss] * dinv[dd]));
            }
        }
    }
}

// ---------------- GEMM1 (MFMA): Hbf = bf16(X @ W1 + b1), 64-row tiles ----------------
__global__ __launch_bounds__(256) void gemm1_mfma_kernel(const float* __restrict__ X,
                                                         const uint* __restrict__ W1t,
                                                         const float* __restrict__ bias,
                                                         ushort* __restrict__ Hbf) {
    __shared__ uint lds[(64 + 128) * XS_STRIDE];
    uint* Xs = lds;
    uint* Ws = lds + 64 * XS_STRIDE;
    const int t = threadIdx.x;
    const int rowBase = blockIdx.x * 64;

    {
        int r = t >> 2, q = t & 3;
        int arow = rowBase + r;
        uint* xd = &Xs[r * XS_STRIDE + q * 16];
        if (arow < N_NODES) {
            const float4* xp = (const float4*)&X[arow * 128 + q * 32];
#pragma unroll
            for (int i = 0; i < 8; ++i) {
                float4 v = xp[i];
                xd[2 * i]     = pack_bf2(v.x, v.y);
                xd[2 * i + 1] = pack_bf2(v.z, v.w);
            }
        } else {
#pragma unroll
            for (int i = 0; i < 16; ++i) xd[i] = 0u;
        }
    }
    {
        int n = t >> 1, half = t & 1;
        const uint4* wp = (const uint4*)&W1t[n * 64 + half * 32];
        uint* wd = &Ws[n * XS_STRIDE + half * 32];
#pragma unroll
        for (int i = 0; i < 8; ++i) *(uint4*)&wd[i * 4] = wp[i];
    }
    __syncthreads();

    const int wv = t >> 6, lane = t & 63;
    const int lr = lane & 15;
    const int ko = (lane >> 4) * 4;
    const int m0 = wv * 16;
    floatx4 acc[8];
#pragma unroll
    for (int j = 0; j < 8; ++j) acc[j] = (floatx4){0.f, 0.f, 0.f, 0.f};

#pragma unroll
    for (int ks = 0; ks < 4; ++ks) {
        const int kb = ks * 16 + ko;
        bf16x8 a = *(bf16x8*)&Xs[(m0 + lr) * XS_STRIDE + kb];
#pragma unroll
        for (int j = 0; j < 8; ++j) {
            bf16x8 b = *(bf16x8*)&Ws[(j * 16 + lr) * XS_STRIDE + kb];
            acc[j] = __builtin_amdgcn_mfma_f32_16x16x32_bf16(a, b, acc[j], 0, 0, 0);
        }
    }
    const int rbase = rowBase + m0 + (lane >> 4) * 4;
#pragma unroll
    for (int j = 0; j < 8; ++j) {
        const int col = j * 16 + lr;
        const float bb = bias[col];
#pragma unroll
        for (int r = 0; r < 4; ++r) {
            int row = rbase + r;
            if (row < N_NODES) Hbf[row * 128 + col] = bf1(acc[j][r] + bb);
        }
    }
}

// ---------------- GEMM2 (MFMA): Hbf = bf16(relu(bn(bf16 Hin)) @ W2 + b2) ------------
__global__ __launch_bounds__(256) void gemm2_mfma_kernel(const uint* __restrict__ Hin,
                                                         const uint* __restrict__ W2t,
                                                         const float* __restrict__ bias,
                                                         const float* __restrict__ scale,
                                                         const float* __restrict__ shift,
                                                         ushort* __restrict__ Hbf) {
    __shared__ uint lds[(64 + 64) * XS_STRIDE];
    uint* Xs = lds;
    uint* Ws = lds + 64 * XS_STRIDE;
    const int t = threadIdx.x;
    const int rowBase = blockIdx.x * 64;

    {
        int r = t >> 2, q = t & 3;
        int arow = rowBase + r;
        uint* xd = &Xs[r * XS_STRIDE + q * 16];
        if (arow < N_NODES) {
            const uint* hp = &Hin[arow * 64 + q * 16];
#pragma unroll
            for (int i = 0; i < 16; ++i) {
                uint u = hp[i];
                int m = q * 16 + i;
                float2 sc = *(const float2*)&scale[2 * m];
                float2 sh = *(const float2*)&shift[2 * m];
                float a0 = fmaxf(0.f, bfl(u) * sc.x + sh.x);
                float a1 = fmaxf(0.f, bfh(u) * sc.y + sh.y);
                xd[i] = pack_bf2(a0, a1);
            }
        } else {
#pragma unroll
            for (int i = 0; i < 16; ++i) xd[i] = 0u;
        }
    }
    if (t < 128) {
        int n = t >> 1, half = t & 1;
        const uint4* wp = (const uint4*)&W2t[n * 64 + half * 32];
        uint* wd = &Ws[n * XS_STRIDE + half * 32];
#pragma unroll
        for (int i = 0; i < 8; ++i) *(uint4*)&wd[i * 4] = wp[i];
    }
    __syncthreads();

    const int wv = t >> 6, lane = t & 63;
    const int lr = lane & 15;
    const int ko = (lane >> 4) * 4;
    const int m0 = wv * 16;
    floatx4 acc[4];
#pragma unroll
    for (int j = 0; j < 4; ++j) acc[j] = (floatx4){0.f, 0.f, 0.f, 0.f};

#pragma unroll
    for (int ks = 0; ks < 4; ++ks) {
        const int kb = ks * 16 + ko;
        bf16x8 a = *(bf16x8*)&Xs[(m0 + lr) * XS_STRIDE + kb];
#pragma unroll
        for (int j = 0; j < 4; ++j) {
            bf16x8 b = *(bf16x8*)&Ws[(j * 16 + lr) * XS_STRIDE + kb];
            acc[j] = __builtin_amdgcn_mfma_f32_16x16x32_bf16(a, b, acc[j], 0, 0, 0);
        }
    }
    const int rbase = rowBase + m0 + (lane >> 4) * 4;
#pragma unroll
    for (int j = 0; j < 4; ++j) {
        const int col = j * 16 + lr;
        const float bb = bias[col];
#pragma unroll
        for (int r = 0; r < 4; ++r) {
            int row = rbase + r;
            if (row < N_NODES) Hbf[row * 64 + col] = bf1(acc[j][r] + bb);
        }
    }
}

// ---------------- CSR gather SpMM over bf16 H, fp32 accumulate ----------------
// epair loaded 2-edges-per-int4; gather loop unrolled to 8 outstanding loads.
template <int C, bool OUT_BF16>
__global__ __launch_bounds__(256) void spmm_bf16_kernel(const int* __restrict__ rowptr,
                                                        const int2* __restrict__ epair,
                                                        const float* __restrict__ dinv,
                                                        const uint* __restrict__ H,
                                                        void* __restrict__ outv) {
    constexpr int LPR = C / 8;        // lanes per row
    constexpr int RPB = 256 / LPR;    // rows per block
    constexpr int US  = C / 2;        // uint row stride
    const int t = threadIdx.x;
    const int lane = t % LPR;
    const int row = blockIdx.x * RPB + t / LPR;
    if (row >= N_NODES) return;
    const int cu = lane * 4;
    const float di = dinv[row];

    float acc[8];
    {
        uint4 hv = *(const uint4*)&H[row * US + cu];
        float w = di * di;
        acc[0] = w * bfl(hv.x); acc[1] = w * bfh(hv.x);
        acc[2] = w * bfl(hv.y); acc[3] = w * bfh(hv.y);
        acc[4] = w * bfl(hv.z); acc[5] = w * bfh(hv.z);
        acc[6] = w * bfl(hv.w); acc[7] = w * bfh(hv.w);
    }
    const int e0 = rowptr[row], e1 = rowptr[row + 1];
    int e = e0;
    if ((e & 1) && e < e1) {
        int2 p = epair[e];
        uint4 h = *(const uint4*)&H[p.x * US + cu];
        acc8(acc, h, __int_as_float(p.y));
        ++e;
    }
    const int4* ep4 = (const int4*)epair;
    for (; e + 8 <= e1; e += 8) {
        int4 qa = ep4[(e >> 1) + 0];
        int4 qb = ep4[(e >> 1) + 1];
        int4 qc = ep4[(e >> 1) + 2];
        int4 qd = ep4[(e >> 1) + 3];
        uint4 h0 = *(const uint4*)&H[qa.x * US + cu];
        uint4 h1 = *(const uint4*)&H[qa.z * US + cu];
        uint4 h2 = *(const uint4*)&H[qb.x * US + cu];
        uint4 h3 = *(const uint4*)&H[qb.z * US + cu];
        uint4 h4 = *(const uint4*)&H[qc.x * US + cu];
        uint4 h5 = *(const uint4*)&H[qc.z * US + cu];
        uint4 h6 = *(const uint4*)&H[qd.x * US + cu];
        uint4 h7 = *(const uint4*)&H[qd.z * US + cu];
        acc8(acc, h0, __int_as_float(qa.y));
        acc8(acc, h1, __int_as_float(qa.w));
        acc8(acc, h2, __int_as_float(qb.y));
        acc8(acc, h3, __int_as_float(qb.w));
        acc8(acc, h4, __int_as_float(qc.y));
        acc8(acc, h5, __int_as_float(qc.w));
        acc8(acc, h6, __int_as_float(qd.y));
        acc8(acc, h7, __int_as_float(qd.w));
    }
    for (; e + 2 <= e1; e += 2) {
        int4 q = ep4[e >> 1];
        uint4 h0 = *(const uint4*)&H[q.x * US + cu];
        uint4 h1 = *(const uint4*)&H[q.z * US + cu];
        acc8(acc, h0, __int_as_float(q.y));
        acc8(acc, h1, __int_as_float(q.w));
    }
    if (e < e1) {
        int2 p = epair[e];
        uint4 h = *(const uint4*)&H[p.x * US + cu];
        acc8(acc, h, __int_as_float(p.y));
    }
    if (OUT_BF16) {
        uint4 o;
        o.x = pack_bf2(acc[0], acc[1]);
        o.y = pack_bf2(acc[2], acc[3]);
        o.z = pack_bf2(acc[4], acc[5]);
        o.w = pack_bf2(acc[6], acc[7]);
        *(uint4*)&((uint*)outv)[row * US + cu] = o;
    } else {
        float* out = (float*)outv;
        *(float4*)&out[row * C + lane * 8]     = make_float4(acc[0], acc[1], acc[2], acc[3]);
        *(float4*)&out[row * C + lane * 8 + 4] = make_float4(acc[4], acc[5], acc[6], acc[7]);
    }
}

// ---------------- BN statistics over bf16 h1agg ----------------
__global__ __launch_bounds__(256) void bn_stats_kernel(const uint* __restrict__ H,
                                                       float* __restrict__ sum,
                                                       float* __restrict__ sumsq) {
    int uc = threadIdx.x & 63;       // uint column (2 channels)
    int quarter = threadIdx.x >> 6;
    float s0 = 0.f, q0 = 0.f, s1 = 0.f, q1 = 0.f;
    for (int r = blockIdx.x * 4 + quarter; r < N_NODES; r += 512) {
        uint u = H[r * 64 + uc];
        float a = bfl(u), b = bfh(u);
        s0 += a; q0 += a * a;
        s1 += b; q1 += b * b;
    }
    __shared__ float red[4][256];
    red[0][threadIdx.x] = s0; red[1][threadIdx.x] = q0;
    red[2][threadIdx.x] = s1; red[3][threadIdx.x] = q1;
    __syncthreads();
    if (quarter == 0) {
        float ts0 = 0.f, tq0 = 0.f, ts1 = 0.f, tq1 = 0.f;
#pragma unroll
        for (int k = 0; k < 4; ++k) {
            ts0 += red[0][k * 64 + uc]; tq0 += red[1][k * 64 + uc];
            ts1 += red[2][k * 64 + uc]; tq1 += red[3][k * 64 + uc];
        }
        atomicAdd(&sum[2 * uc], ts0);
        atomicAdd(&sum[2 * uc + 1], ts1);
        atomicAdd(&sumsq[2 * uc], tq0);
        atomicAdd(&sumsq[2 * uc + 1], tq1);
    }
}

__global__ void bn_finalize_kernel(const float* __restrict__ sum,
                                   const float* __restrict__ sumsq,
                                   const float* __restrict__ gamma,
                                   const float* __restrict__ beta,
                                   float* __restrict__ scale,
                                   float* __restrict__ shift) {
    int c = threadIdx.x;
    if (c < 128) {
        float mean = sum[c] * (1.0f / N_NODES);
        float var = sumsq[c] * (1.0f / N_NODES) - mean * mean;
        float sc = gamma[c] * rsqrtf(var + BN_EPS);
        scale[c] = sc;
        shift[c] = beta[c] - mean * sc;
    }
}

extern "C" void kernel_launch(void* const* d_in, const int* in_sizes, int n_in,
                              void* d_out, int out_size, void* d_ws, size_t ws_size,
                              hipStream_t stream) {
    const float* x     = (const float*)d_in[0];
    const int*   ei    = (const int*)d_in[1];
    const float* W1    = (const float*)d_in[2];
    const float* b1    = (const float*)d_in[3];
    const float* gamma = (const float*)d_in[4];
    const float* beta  = (const float*)d_in[5];
    const float* W2    = (const float*)d_in[6];
    const float* b2    = (const float*)d_in[7];
    float* out = (float*)d_out;
    const int* src = ei;
    const int* dst = ei + N_EDGES;

    // ---- workspace layout (4-byte words) ----
    float* ws     = (float*)d_ws;
    float* dinv   = ws;                              // NPAD
    float* stats  = ws + NPAD;                       // 512
    int*   psum   = (int*)(ws + NPAD + 512);         // 128
    int*   rowcnt = psum + 128;                      // NPAD
    int*   rowptr = rowcnt + NPAD;                   // NPAD
    float* big    = (float*)(rowptr + NPAD);
    // BIG region (word offsets), lifetime-disjoint aliases:
    //   epair    @ 0         [1.6M]     (fill -> spmms)
    //   part_cnt @ 1.6M      [2.097M]   (dead after cursor_init)
    //   part_deg @ 3.7M      [2.097M]   (dead after dinv_rowcnt)
    //   cursor   @ 5.8M      [4.194M]   (dead after fill, precedes all h1agg writes)
    //   h1bf     @ 1.6M      [3.2M]     (gemm1 -> spmm1; aliases part arrays, dead by then)
    //   h1agg    @ 4.8M      [1.6M]     (spmm1 bf16 out; aliases cursor region, dead by then)
    //   W1t/W2t  @ 10.0M     [12K]
    int2*   epair    = (int2*)big;
    ushort* part_cnt = (ushort*)(big + 1600000);
    ushort* part_deg = (ushort*)(big + 3700000);
    int*    cursor   = (int*)(big + 5800000);
    ushort* h1bf     = (ushort*)(big + 1600000);
    uint*   h1agg    = (uint*)(big + 4800000);       // bf16 x128, packed pairs
    ushort* h2bf     = h1bf;                         // 64ch, fits in h1bf region
    uint*   W1t      = (uint*)(big + 10000000);
    uint*   W2t      = W1t + 8192;
    float* sum    = stats;
    float* sumsq  = stats + 128;
    float* scale  = stats + 256;
    float* shift  = stats + 384;

    hipMemsetAsync(stats, 0, 512 * sizeof(float), stream);

    prep_w_kernel<<<48, 256, 0, stream>>>(W1, W2, W1t, W2t);

    count_hist_kernel<<<S_SLICES * R_RANGES, 256, 0, stream>>>(src, dst, part_cnt, part_deg);
    dinv_rowcnt_kernel<<<NPAD / 512, 256, 0, stream>>>(part_deg, part_cnt, dinv, rowcnt);

    scan1_kernel<<<SCAN_BLOCKS, 512, 0, stream>>>(rowcnt, rowptr, psum);
    scan2_kernel<<<1, 64, 0, stream>>>(psum);
    cursor_init_kernel<<<NPAD / 512, 256, 0, stream>>>(rowcnt, rowptr, psum, part_cnt, cursor);
    fill_lds_kernel<<<S_SLICES * R_RANGES, 256, 0, stream>>>(src, dst, dinv, cursor, epair);

    gemm1_mfma_kernel<<<(N_NODES + 63) / 64, 256, 0, stream>>>(x, W1t, b1, h1bf);

    spmm_bf16_kernel<128, true><<<(N_NODES + 15) / 16, 256, 0, stream>>>(
        rowptr, epair, dinv, (const uint*)h1bf, (void*)h1agg);

    bn_stats_kernel<<<128, 256, 0, stream>>>(h1agg, sum, sumsq);
    bn_finalize_kernel<<<1, 128, 0, stream>>>(sum, sumsq, gamma, beta, scale, shift);

    gemm2_mfma_kernel<<<(N_NODES + 63) / 64, 256, 0, stream>>>(h1agg, W2t, b2, scale, shift, h2bf);

    spmm_bf16_kernel<64, false><<<(N_NODES + 31) / 32, 256, 0, stream>>>(
        rowptr, epair, dinv, (const uint*)h2bf, (void*)out);
}

// Round 12
// 245.833 us; speedup vs baseline: 1.2720x; 1.0443x over previous
//
#include <hip/hip_runtime.h>

#define N_NODES 50000
#define N_EDGES 800000
#define BN_EPS 1e-5f
#define NPAD 50176          // N_NODES padded to 98*512
#define SCAN_BLOCKS 98      // 98*512 = 50176

// CSR-build tiling: 64 edge slices x 4 node ranges of 16384 bins (packed LDS counters)
#define S_SLICES 64
#define R_RANGES 4
#define BINS 16384
#define NP4 (R_RANGES * BINS)        // 65536 bins per slice
#define ES (N_EDGES / S_SLICES)      // 12500 edges per slice (div by 4)

#define XS_STRIDE 68                 // LDS row stride in uints: bank spread

typedef unsigned int uint;
typedef unsigned short ushort;
typedef float floatx4 __attribute__((ext_vector_type(4)));
typedef short bf16x8 __attribute__((ext_vector_type(8)));

// ---- bf16 helpers ----
__device__ __forceinline__ float bfl(uint u) { return __uint_as_float(u << 16); }
__device__ __forceinline__ float bfh(uint u) { return __uint_as_float(u & 0xffff0000u); }
__device__ __forceinline__ uint pack_bf2(float a, float b) {
    uint ua = __float_as_uint(a), ub = __float_as_uint(b);
    ua += 0x7fffu + ((ua >> 16) & 1u);   // RNE
    ub += 0x7fffu + ((ub >> 16) & 1u);
    return (ua >> 16) | (ub & 0xffff0000u);
}
__device__ __forceinline__ ushort bf1(float x) {
    uint u = __float_as_uint(x);
    u += 0x7fffu + ((u >> 16) & 1u);
    return (ushort)(u >> 16);
}
__device__ __forceinline__ void acc8(float* a, uint4 h, float w) {
    a[0] += w * bfl(h.x); a[1] += w * bfh(h.x);
    a[2] += w * bfl(h.y); a[3] += w * bfh(h.y);
    a[4] += w * bfl(h.z); a[5] += w * bfh(h.z);
    a[6] += w * bfl(h.w); a[7] += w * bfh(h.w);
}

// ---------------- weight prep: W1[k][n]->W1t bf16[n][k], W2 likewise ----------------
__global__ __launch_bounds__(256) void prep_w_kernel(const float* __restrict__ W1,
                                                     const float* __restrict__ W2,
                                                     uint* __restrict__ W1t,
                                                     uint* __restrict__ W2t) {
    int t = blockIdx.x * 256 + threadIdx.x;
    if (t < 8192) {
        int n = t >> 6, kk = t & 63;
        W1t[t] = pack_bf2(W1[(2 * kk) * 128 + n], W1[(2 * kk + 1) * 128 + n]);
    } else if (t < 12288) {
        int u = t - 8192;
        int n = u >> 6, kk = u & 63;
        W2t[u] = pack_bf2(W2[(2 * kk) * 64 + n], W2[(2 * kk + 1) * 64 + n]);
    }
}

// ---------------- count: packed LDS histograms per (slice, range), int4 edge loads ---
__global__ __launch_bounds__(256) void count_hist_kernel(const int* __restrict__ src,
                                                         const int* __restrict__ dst,
                                                         ushort* __restrict__ part_cnt,
                                                         ushort* __restrict__ part_deg) {
    __shared__ uint cnt_lds[BINS / 2];   // 2 bins per uint (16-bit fields)
    __shared__ uint deg_lds[BINS / 2];
    const int s = blockIdx.x / R_RANGES;
    const int r = blockIdx.x % R_RANGES;
    const int base = r * BINS;
    for (int j = threadIdx.x; j < BINS / 2; j += 256) { cnt_lds[j] = 0u; deg_lds[j] = 0u; }
    __syncthreads();
    const int4* s4 = (const int4*)(src + s * ES);
    const int4* d4 = (const int4*)(dst + s * ES);
#pragma unroll 2
    for (int g = threadIdx.x; g < ES / 4; g += 256) {
        int4 sv = s4[g];
        int4 dv = d4[g];
#pragma unroll
        for (int k = 0; k < 4; ++k) {
            int ss = (&sv.x)[k], dd = (&dv.x)[k];
            if (ss != dd) {
                int a = ss - base;
                if ((unsigned)a < (unsigned)BINS)
                    atomicAdd(&cnt_lds[a >> 1], 1u << ((a & 1) * 16));
                int b = dd - base;
                if ((unsigned)b < (unsigned)BINS)
                    atomicAdd(&deg_lds[b >> 1], 1u << ((b & 1) * 16));
            }
        }
    }
    __syncthreads();
    uint* pc = (uint*)&part_cnt[s * NP4 + base];
    uint* pd = (uint*)&part_deg[s * NP4 + base];
    for (int j = threadIdx.x; j < BINS / 2; j += 256) { pc[j] = cnt_lds[j]; pd[j] = deg_lds[j]; }
}

// ---------------- reduce partials + block-local scan (merged dinv_rowcnt + scan1) -----
// Per block: 512 nodes. Writes dinv, rowcnt, rowptr (inclusive-within-block), psum[blk].
// Block 0 additionally zeros the BN stats accumulators.
__global__ __launch_bounds__(256) void reduce_scan_kernel(const ushort* __restrict__ part_deg,
                                                          const ushort* __restrict__ part_cnt,
                                                          float* __restrict__ dinv,
                                                          int* __restrict__ rowcnt,
                                                          int* __restrict__ rowptr,
                                                          int* __restrict__ psum,
                                                          float* __restrict__ stats) {
    const int t = threadIdx.x;
    if (blockIdx.x == 0) stats[t] = 0.f;   // sum[128] + sumsq[128]
    const int i = blockIdx.x * 512 + 2 * t;
    uint dg0 = 0, dg1 = 0, rc0 = 0, rc1 = 0;
#pragma unroll 8
    for (int s = 0; s < S_SLICES; ++s) {
        uint vd = *(const uint*)&part_deg[s * NP4 + i];
        uint vc = *(const uint*)&part_cnt[s * NP4 + i];
        dg0 += vd & 0xffffu; dg1 += vd >> 16;
        rc0 += vc & 0xffffu; rc1 += vc >> 16;
    }
    *(int2*)&rowcnt[i] = make_int2((int)rc0, (int)rc1);
    if (i < N_NODES) dinv[i] = rsqrtf((float)dg0 + 1.0f);
    if (i + 1 < N_NODES) dinv[i + 1] = rsqrtf((float)dg1 + 1.0f);

    __shared__ int bs[256];
    const int pair = (int)(rc0 + rc1);
    bs[t] = pair;
    __syncthreads();
#pragma unroll
    for (int off = 1; off < 256; off <<= 1) {
        int x = (t >= off) ? bs[t - off] : 0;
        __syncthreads();
        bs[t] += x;
        __syncthreads();
    }
    const int excl = bs[t] - pair;
    *(int2*)&rowptr[i] = make_int2(excl + (int)rc0, excl + pair);
    if (t == 255) psum[blockIdx.x] = bs[255];
}

// ---------------- finalize rowptr (exclusive) + per-(slice,node) cursor bases --------
// psum prefix computed in-block (inlined scan2).
__global__ __launch_bounds__(256) void cursor_init_kernel(const int* __restrict__ rowcnt,
                                                          int* __restrict__ rowptr,
                                                          const int* __restrict__ psum,
                                                          const ushort* __restrict__ part_cnt,
                                                          int* __restrict__ cursor) {
    __shared__ int pbuf[SCAN_BLOCKS];
    __shared__ int lps;
    const int t = threadIdx.x;
    if (t < SCAN_BLOCKS) pbuf[t] = psum[t];
    __syncthreads();
    if (t == 0) {
        int acc = 0;
        for (int j = 0; j < (int)blockIdx.x; ++j) acc += pbuf[j];
        lps = acc;
    }
    __syncthreads();
    const int ps = lps;
    const int i = blockIdx.x * 512 + 2 * t;
    int b0 = rowptr[i] - rowcnt[i] + ps;
    int b1 = rowptr[i + 1] - rowcnt[i + 1] + ps;
    *(int2*)&rowptr[i] = make_int2(b0, b1);
#pragma unroll 8
    for (int s = 0; s < S_SLICES; ++s) {
        *(int2*)&cursor[s * NP4 + i] = make_int2(b0, b1);
        uint vc = *(const uint*)&part_cnt[s * NP4 + i];
        b0 += (int)(vc & 0xffffu);
        b1 += (int)(vc >> 16);
    }
}

// ---------------- fill CSR via LDS cursors, int4 edge loads ----------------
__global__ __launch_bounds__(256) void fill_lds_kernel(const int* __restrict__ src,
                                                       const int* __restrict__ dst,
                                                       const float* __restrict__ dinv,
                                                       const int* __restrict__ cursor,
                                                       int2* __restrict__ epair) {
    __shared__ int curs[BINS];   // 64 KB
    const int s = blockIdx.x / R_RANGES;
    const int r = blockIdx.x % R_RANGES;
    const int base = r * BINS;
    const int* gc = &cursor[s * NP4 + base];
    for (int j = threadIdx.x; j < BINS; j += 256) curs[j] = gc[j];
    __syncthreads();
    const int4* s4 = (const int4*)(src + s * ES);
    const int4* d4 = (const int4*)(dst + s * ES);
#pragma unroll 2
    for (int g = threadIdx.x; g < ES / 4; g += 256) {
        int4 sv = s4[g];
        int4 dv = d4[g];
#pragma unroll
        for (int k = 0; k < 4; ++k) {
            int ss = (&sv.x)[k], dd = (&dv.x)[k];
            int a = ss - base;
            if (ss != dd && (unsigned)a < (unsigned)BINS) {
                int pos = atomicAdd(&curs[a], 1);
                epair[pos] = make_int2(dd, __float_as_int(dinv[ss] * dinv[dd]));
            }
        }
    }
}

// ---------------- GEMM1 (MFMA): Hbf = bf16(X @ W1 + b1), 64-row tiles ----------------
__global__ __launch_bounds__(256) void gemm1_mfma_kernel(const float* __restrict__ X,
                                                         const uint* __restrict__ W1t,
                                                         const float* __restrict__ bias,
                                                         ushort* __restrict__ Hbf) {
    __shared__ uint lds[(64 + 128) * XS_STRIDE];
    uint* Xs = lds;
    uint* Ws = lds + 64 * XS_STRIDE;
    const int t = threadIdx.x;
    const int rowBase = blockIdx.x * 64;

    {
        int r = t >> 2, q = t & 3;
        int arow = rowBase + r;
        uint* xd = &Xs[r * XS_STRIDE + q * 16];
        if (arow < N_NODES) {
            const float4* xp = (const float4*)&X[arow * 128 + q * 32];
#pragma unroll
            for (int i = 0; i < 8; ++i) {
                float4 v = xp[i];
                xd[2 * i]     = pack_bf2(v.x, v.y);
                xd[2 * i + 1] = pack_bf2(v.z, v.w);
            }
        } else {
#pragma unroll
            for (int i = 0; i < 16; ++i) xd[i] = 0u;
        }
    }
    {
        int n = t >> 1, half = t & 1;
        const uint4* wp = (const uint4*)&W1t[n * 64 + half * 32];
        uint* wd = &Ws[n * XS_STRIDE + half * 32];
#pragma unroll
        for (int i = 0; i < 8; ++i) *(uint4*)&wd[i * 4] = wp[i];
    }
    __syncthreads();

    const int wv = t >> 6, lane = t & 63;
    const int lr = lane & 15;
    const int ko = (lane >> 4) * 4;
    const int m0 = wv * 16;
    floatx4 acc[8];
#pragma unroll
    for (int j = 0; j < 8; ++j) acc[j] = (floatx4){0.f, 0.f, 0.f, 0.f};

#pragma unroll
    for (int ks = 0; ks < 4; ++ks) {
        const int kb = ks * 16 + ko;
        bf16x8 a = *(bf16x8*)&Xs[(m0 + lr) * XS_STRIDE + kb];
#pragma unroll
        for (int j = 0; j < 8; ++j) {
            bf16x8 b = *(bf16x8*)&Ws[(j * 16 + lr) * XS_STRIDE + kb];
            acc[j] = __builtin_amdgcn_mfma_f32_16x16x32_bf16(a, b, acc[j], 0, 0, 0);
        }
    }
    const int rbase = rowBase + m0 + (lane >> 4) * 4;
#pragma unroll
    for (int j = 0; j < 8; ++j) {
        const int col = j * 16 + lr;
        const float bb = bias[col];
#pragma unroll
        for (int r = 0; r < 4; ++r) {
            int row = rbase + r;
            if (row < N_NODES) Hbf[row * 128 + col] = bf1(acc[j][r] + bb);
        }
    }
}

// ---------------- GEMM2 (MFMA): Hbf = bf16(relu(bn(bf16 Hin)) @ W2 + b2) ------------
// BN finalize inlined: scale/shift computed per block from sum/sumsq/gamma/beta.
__global__ __launch_bounds__(256) void gemm2_mfma_kernel(const uint* __restrict__ Hin,
                                                         const uint* __restrict__ W2t,
                                                         const float* __restrict__ bias,
                                                         const float* __restrict__ sum,
                                                         const float* __restrict__ sumsq,
                                                         const float* __restrict__ gamma,
                                                         const float* __restrict__ beta,
                                                         ushort* __restrict__ Hbf) {
    __shared__ uint lds[(64 + 64) * XS_STRIDE];
    __shared__ float sc_sh[128], sh_sh[128];
    uint* Xs = lds;
    uint* Ws = lds + 64 * XS_STRIDE;
    const int t = threadIdx.x;
    const int rowBase = blockIdx.x * 64;

    if (t < 128) {
        float mean = sum[t] * (1.0f / N_NODES);
        float var = sumsq[t] * (1.0f / N_NODES) - mean * mean;
        float sc = gamma[t] * rsqrtf(var + BN_EPS);
        sc_sh[t] = sc;
        sh_sh[t] = beta[t] - mean * sc;
    }
    // stage W2t: 64 n-rows x 64 uints (threads 128..255)
    if (t >= 128) {
        int u = t - 128;
        int n = u >> 1, half = u & 1;
        const uint4* wp = (const uint4*)&W2t[n * 64 + half * 32];
        uint* wd = &Ws[n * XS_STRIDE + half * 32];
#pragma unroll
        for (int i = 0; i < 8; ++i) *(uint4*)&wd[i * 4] = wp[i];
    }
    __syncthreads();

    {
        int r = t >> 2, q = t & 3;
        int arow = rowBase + r;
        uint* xd = &Xs[r * XS_STRIDE + q * 16];
        if (arow < N_NODES) {
            const uint* hp = &Hin[arow * 64 + q * 16];
#pragma unroll
            for (int i = 0; i < 16; ++i) {
                uint u = hp[i];
                int m = q * 16 + i;
                float a0 = fmaxf(0.f, bfl(u) * sc_sh[2 * m] + sh_sh[2 * m]);
                float a1 = fmaxf(0.f, bfh(u) * sc_sh[2 * m + 1] + sh_sh[2 * m + 1]);
                xd[i] = pack_bf2(a0, a1);
            }
        } else {
#pragma unroll
            for (int i = 0; i < 16; ++i) xd[i] = 0u;
        }
    }
    __syncthreads();

    const int wv = t >> 6, lane = t & 63;
    const int lr = lane & 15;
    const int ko = (lane >> 4) * 4;
    const int m0 = wv * 16;
    floatx4 acc[4];
#pragma unroll
    for (int j = 0; j < 4; ++j) acc[j] = (floatx4){0.f, 0.f, 0.f, 0.f};

#pragma unroll
    for (int ks = 0; ks < 4; ++ks) {
        const int kb = ks * 16 + ko;
        bf16x8 a = *(bf16x8*)&Xs[(m0 + lr) * XS_STRIDE + kb];
#pragma unroll
        for (int j = 0; j < 4; ++j) {
            bf16x8 b = *(bf16x8*)&Ws[(j * 16 + lr) * XS_STRIDE + kb];
            acc[j] = __builtin_amdgcn_mfma_f32_16x16x32_bf16(a, b, acc[j], 0, 0, 0);
        }
    }
    const int rbase = rowBase + m0 + (lane >> 4) * 4;
#pragma unroll
    for (int j = 0; j < 4; ++j) {
        const int col = j * 16 + lr;
        const float bb = bias[col];
#pragma unroll
        for (int r = 0; r < 4; ++r) {
            int row = rbase + r;
            if (row < N_NODES) Hbf[row * 64 + col] = bf1(acc[j][r] + bb);
        }
    }
}

// ---------------- CSR gather SpMM over bf16 H, fp32 accumulate ----------------
// epair loaded 2-edges-per-int4; gather loop unrolled to 8 outstanding loads.
template <int C, bool OUT_BF16>
__global__ __launch_bounds__(256) void spmm_bf16_kernel(const int* __restrict__ rowptr,
                                                        const int2* __restrict__ epair,
                                                        const float* __restrict__ dinv,
                                                        const uint* __restrict__ H,
                                                        void* __restrict__ outv) {
    constexpr int LPR = C / 8;        // lanes per row
    constexpr int RPB = 256 / LPR;    // rows per block
    constexpr int US  = C / 2;        // uint row stride
    const int t = threadIdx.x;
    const int lane = t % LPR;
    const int row = blockIdx.x * RPB + t / LPR;
    if (row >= N_NODES) return;
    const int cu = lane * 4;
    const float di = dinv[row];

    float acc[8];
    {
        uint4 hv = *(const uint4*)&H[row * US + cu];
        float w = di * di;
        acc[0] = w * bfl(hv.x); acc[1] = w * bfh(hv.x);
        acc[2] = w * bfl(hv.y); acc[3] = w * bfh(hv.y);
        acc[4] = w * bfl(hv.z); acc[5] = w * bfh(hv.z);
        acc[6] = w * bfl(hv.w); acc[7] = w * bfh(hv.w);
    }
    const int e0 = rowptr[row], e1 = rowptr[row + 1];
    int e = e0;
    if ((e & 1) && e < e1) {
        int2 p = epair[e];
        uint4 h = *(const uint4*)&H[p.x * US + cu];
        acc8(acc, h, __int_as_float(p.y));
        ++e;
    }
    const int4* ep4 = (const int4*)epair;
    for (; e + 8 <= e1; e += 8) {
        int4 qa = ep4[(e >> 1) + 0];
        int4 qb = ep4[(e >> 1) + 1];
        int4 qc = ep4[(e >> 1) + 2];
        int4 qd = ep4[(e >> 1) + 3];
        uint4 h0 = *(const uint4*)&H[qa.x * US + cu];
        uint4 h1 = *(const uint4*)&H[qa.z * US + cu];
        uint4 h2 = *(const uint4*)&H[qb.x * US + cu];
        uint4 h3 = *(const uint4*)&H[qb.z * US + cu];
        uint4 h4 = *(const uint4*)&H[qc.x * US + cu];
        uint4 h5 = *(const uint4*)&H[qc.z * US + cu];
        uint4 h6 = *(const uint4*)&H[qd.x * US + cu];
        uint4 h7 = *(const uint4*)&H[qd.z * US + cu];
        acc8(acc, h0, __int_as_float(qa.y));
        acc8(acc, h1, __int_as_float(qa.w));
        acc8(acc, h2, __int_as_float(qb.y));
        acc8(acc, h3, __int_as_float(qb.w));
        acc8(acc, h4, __int_as_float(qc.y));
        acc8(acc, h5, __int_as_float(qc.w));
        acc8(acc, h6, __int_as_float(qd.y));
        acc8(acc, h7, __int_as_float(qd.w));
    }
    for (; e + 2 <= e1; e += 2) {
        int4 q = ep4[e >> 1];
        uint4 h0 = *(const uint4*)&H[q.x * US + cu];
        uint4 h1 = *(const uint4*)&H[q.z * US + cu];
        acc8(acc, h0, __int_as_float(q.y));
        acc8(acc, h1, __int_as_float(q.w));
    }
    if (e < e1) {
        int2 p = epair[e];
        uint4 h = *(const uint4*)&H[p.x * US + cu];
        acc8(acc, h, __int_as_float(p.y));
    }
    if (OUT_BF16) {
        uint4 o;
        o.x = pack_bf2(acc[0], acc[1]);
        o.y = pack_bf2(acc[2], acc[3]);
        o.z = pack_bf2(acc[4], acc[5]);
        o.w = pack_bf2(acc[6], acc[7]);
        *(uint4*)&((uint*)outv)[row * US + cu] = o;
    } else {
        float* out = (float*)outv;
        *(float4*)&out[row * C + lane * 8]     = make_float4(acc[0], acc[1], acc[2], acc[3]);
        *(float4*)&out[row * C + lane * 8 + 4] = make_float4(acc[4], acc[5], acc[6], acc[7]);
    }
}

// ---------------- BN statistics over bf16 h1agg ----------------
__global__ __launch_bounds__(256) void bn_stats_kernel(const uint* __restrict__ H,
                                                       float* __restrict__ sum,
                                                       float* __restrict__ sumsq) {
    int uc = threadIdx.x & 63;       // uint column (2 channels)
    int quarter = threadIdx.x >> 6;
    float s0 = 0.f, q0 = 0.f, s1 = 0.f, q1 = 0.f;
    for (int r = blockIdx.x * 4 + quarter; r < N_NODES; r += 512) {
        uint u = H[r * 64 + uc];
        float a = bfl(u), b = bfh(u);
        s0 += a; q0 += a * a;
        s1 += b; q1 += b * b;
    }
    __shared__ float red[4][256];
    red[0][threadIdx.x] = s0; red[1][threadIdx.x] = q0;
    red[2][threadIdx.x] = s1; red[3][threadIdx.x] = q1;
    __syncthreads();
    if (quarter == 0) {
        float ts0 = 0.f, tq0 = 0.f, ts1 = 0.f, tq1 = 0.f;
#pragma unroll
        for (int k = 0; k < 4; ++k) {
            ts0 += red[0][k * 64 + uc]; tq0 += red[1][k * 64 + uc];
            ts1 += red[2][k * 64 + uc]; tq1 += red[3][k * 64 + uc];
        }
        atomicAdd(&sum[2 * uc], ts0);
        atomicAdd(&sum[2 * uc + 1], ts1);
        atomicAdd(&sumsq[2 * uc], tq0);
        atomicAdd(&sumsq[2 * uc + 1], tq1);
    }
}

extern "C" void kernel_launch(void* const* d_in, const int* in_sizes, int n_in,
                              void* d_out, int out_size, void* d_ws, size_t ws_size,
                              hipStream_t stream) {
    const float* x     = (const float*)d_in[0];
    const int*   ei    = (const int*)d_in[1];
    const float* W1    = (const float*)d_in[2];
    const float* b1    = (const float*)d_in[3];
    const float* gamma = (const float*)d_in[4];
    const float* beta  = (const float*)d_in[5];
    const float* W2    = (const float*)d_in[6];
    const float* b2    = (const float*)d_in[7];
    float* out = (float*)d_out;
    const int* src = ei;
    const int* dst = ei + N_EDGES;

    // ---- workspace layout (4-byte words) ----
    float* ws     = (float*)d_ws;
    float* dinv   = ws;                              // NPAD
    float* stats  = ws + NPAD;                       // 256 (sum 128 + sumsq 128)
    int*   psum   = (int*)(ws + NPAD + 512);         // 128
    int*   rowcnt = psum + 128;                      // NPAD
    int*   rowptr = rowcnt + NPAD;                   // NPAD
    float* big    = (float*)(rowptr + NPAD);
    // BIG region (word offsets), lifetime-disjoint aliases:
    //   epair    @ 0         [1.6M]     (fill -> spmms)
    //   part_cnt @ 1.6M      [2.097M]   (dead after cursor_init)
    //   part_deg @ 3.7M      [2.097M]   (dead after reduce_scan)
    //   cursor   @ 5.8M      [4.194M]   (dead after fill, precedes all h1agg writes)
    //   h1bf     @ 1.6M      [3.2M]     (gemm1 -> spmm1; aliases part arrays, dead by then)
    //   h1agg    @ 4.8M      [1.6M]     (spmm1 bf16 out; aliases cursor region, dead by then)
    //   W1t/W2t  @ 10.0M     [12K]
    int2*   epair    = (int2*)big;
    ushort* part_cnt = (ushort*)(big + 1600000);
    ushort* part_deg = (ushort*)(big + 3700000);
    int*    cursor   = (int*)(big + 5800000);
    ushort* h1bf     = (ushort*)(big + 1600000);
    uint*   h1agg    = (uint*)(big + 4800000);       // bf16 x128, packed pairs
    ushort* h2bf     = h1bf;                         // 64ch, fits in h1bf region
    uint*   W1t      = (uint*)(big + 10000000);
    uint*   W2t      = W1t + 8192;
    float* sum    = stats;
    float* sumsq  = stats + 128;

    prep_w_kernel<<<48, 256, 0, stream>>>(W1, W2, W1t, W2t);

    count_hist_kernel<<<S_SLICES * R_RANGES, 256, 0, stream>>>(src, dst, part_cnt, part_deg);
    reduce_scan_kernel<<<SCAN_BLOCKS, 256, 0, stream>>>(part_deg, part_cnt, dinv, rowcnt,
                                                        rowptr, psum, stats);
    cursor_init_kernel<<<SCAN_BLOCKS, 256, 0, stream>>>(rowcnt, rowptr, psum, part_cnt, cursor);
    fill_lds_kernel<<<S_SLICES * R_RANGES, 256, 0, stream>>>(src, dst, dinv, cursor, epair);

    gemm1_mfma_kernel<<<(N_NODES + 63) / 64, 256, 0, stream>>>(x, W1t, b1, h1bf);

    spmm_bf16_kernel<128, true><<<(N_NODES + 15) / 16, 256, 0, stream>>>(
        rowptr, epair, dinv, (const uint*)h1bf, (void*)h1agg);

    bn_stats_kernel<<<128, 256, 0, stream>>>(h1agg, sum, sumsq);

    gemm2_mfma_kernel<<<(N_NODES + 63) / 64, 256, 0, stream>>>(h1agg, W2t, b2, sum, sumsq,
                                                               gamma, beta, h2bf);

    spmm_bf16_kernel<64, false><<<(N_NODES + 31) / 32, 256, 0, stream>>>(
        rowptr, epair, dinv, (const uint*)h2bf, (void*)out);
}